// Round 1
// baseline (1037.687 us; speedup 1.0000x reference)
//
#include <hip/hip_runtime.h>

#define T_STEPS 512
#define BATCH   64
#define HID     64
#define G3      192      // 3*HID
#define DIN     2048

typedef float  f32x4  __attribute__((ext_vector_type(4)));
typedef short  short8 __attribute__((ext_vector_type(8)));

__device__ __forceinline__ unsigned short f2bf(float f) {
    unsigned int u = __builtin_bit_cast(unsigned int, f);
    unsigned int r = u + 0x7fffu + ((u >> 16) & 1u);   // RNE
    return (unsigned short)(r >> 16);
}

__device__ __forceinline__ float sigf(float x) {
    x = fminf(fmaxf(x, -30.f), 30.f);
    return 1.f / (1.f + __expf(-x));
}
__device__ __forceinline__ float tanhf_(float x) {
    float xc = fminf(fmaxf(x, -15.f), 15.f);
    float e = __expf(-2.f * xc);
    return (1.f - e) / (1.f + e);
}

// ---------------- Kernel 1: xi0 = x @ W_ih0^T + b_ih0  (bf16 MFMA) ----------
// M = B*T = 32768 (m = b*512 + t), N = 192, K = 2048.
// Output layout: xi0[(t*64 + b)*192 + g]  (recurrence-friendly).
#define BM  128
#define BK  64
#define LDA 72   // ushorts per row: 64 + 8 pad (breaks bank conflicts)
#define LDB 72

__launch_bounds__(512, 1)
__global__ void proj0_kernel(const float* __restrict__ x,
                             const float* __restrict__ Wih0,
                             const float* __restrict__ bih0,
                             float* __restrict__ xi0)
{
    __shared__ unsigned short Asm[BM * LDA];   // 18432 B
    __shared__ unsigned short Bsm[G3 * LDB];   // 27648 B

    const int tid  = threadIdx.x;
    const int wave = tid >> 6;
    const int lane = tid & 63;
    const int wm   = wave >> 2;      // 0..1  (M half)
    const int wn   = wave & 3;       // 0..3  (N quarter: 48 cols)
    const int m0   = blockIdx.x * BM;
    const int l16  = lane & 15;
    const int lk   = lane >> 4;      // 0..3

    f32x4 acc[4][3];
#pragma unroll
    for (int mi = 0; mi < 4; ++mi)
#pragma unroll
        for (int ni = 0; ni < 3; ++ni)
            acc[mi][ni] = (f32x4){0.f, 0.f, 0.f, 0.f};

    for (int kk = 0; kk < DIN; kk += BK) {
        // stage A tile: x[m0+r][kk+c], 128x64 fp32 -> bf16
#pragma unroll
        for (int it = 0; it < 4; ++it) {
            int fid = tid + it * 512;          // 0..2047 float4 slots
            int r   = fid >> 4;
            int c4  = fid & 15;
            float4 v = *(const float4*)&x[(size_t)(m0 + r) * DIN + kk + c4 * 4];
            uint2 pk;
            pk.x = (unsigned int)f2bf(v.x) | ((unsigned int)f2bf(v.y) << 16);
            pk.y = (unsigned int)f2bf(v.z) | ((unsigned int)f2bf(v.w) << 16);
            *(uint2*)&Asm[r * LDA + c4 * 4] = pk;
        }
        // stage B tile: Wih0[g][kk+c], 192x64 fp32 -> bf16
#pragma unroll
        for (int it = 0; it < 6; ++it) {
            int fid = tid + it * 512;          // 0..3071
            int r   = fid >> 4;
            int c4  = fid & 15;
            float4 v = *(const float4*)&Wih0[(size_t)r * DIN + kk + c4 * 4];
            uint2 pk;
            pk.x = (unsigned int)f2bf(v.x) | ((unsigned int)f2bf(v.y) << 16);
            pk.y = (unsigned int)f2bf(v.z) | ((unsigned int)f2bf(v.w) << 16);
            *(uint2*)&Bsm[r * LDB + c4 * 4] = pk;
        }
        __syncthreads();

#pragma unroll
        for (int ks = 0; ks < 2; ++ks) {
            const int kb = ks * 32 + lk * 8;   // same k-slot map for A and B
            short8 a[4], bfr[3];
#pragma unroll
            for (int mi = 0; mi < 4; ++mi)
                a[mi] = *(const short8*)&Asm[(wm * 64 + mi * 16 + l16) * LDA + kb];
#pragma unroll
            for (int ni = 0; ni < 3; ++ni)
                bfr[ni] = *(const short8*)&Bsm[(wn * 48 + ni * 16 + l16) * LDB + kb];
#pragma unroll
            for (int mi = 0; mi < 4; ++mi)
#pragma unroll
                for (int ni = 0; ni < 3; ++ni)
                    acc[mi][ni] = __builtin_amdgcn_mfma_f32_16x16x32_bf16(
                        a[mi], bfr[ni], acc[mi][ni], 0, 0, 0);
        }
        __syncthreads();
    }

    // epilogue: D layout col=lane&15, row=(lane>>4)*4+reg  [verified m89/m91]
#pragma unroll
    for (int ni = 0; ni < 3; ++ni) {
        int g = wn * 48 + ni * 16 + l16;
        float bias = bih0[g];
#pragma unroll
        for (int mi = 0; mi < 4; ++mi) {
#pragma unroll
            for (int r = 0; r < 4; ++r) {
                int m  = m0 + wm * 64 + mi * 16 + lk * 4 + r;
                int t  = m & 511;
                int bb = m >> 9;
                xi0[(size_t)(t * BATCH + bb) * G3 + g] = acc[mi][ni][r] + bias;
            }
        }
    }
}

// ---------------- Kernel 2: fused 2-layer GRU recurrence + FC ---------------
// One block per batch element. 384 threads:
//   threads 0..191  : hp0(t)       = W_hh0 @ h0(t-1) + b_hh0
//   threads 192..383: xt1(t-1)     = W_ih1 @ h0(t-1) + b_ih1   (same h0 vector!)
//                     hp1(t-1)     = W_hh1 @ h1(t-2) + b_hh1
// Layer 1 runs one step behind layer 0 -> 2 barriers per step.
__launch_bounds__(384, 1)
__global__ void gru_seq_kernel(const float* __restrict__ xi0,
                               const float* __restrict__ Whh0,
                               const float* __restrict__ bhh0,
                               const float* __restrict__ Wih1,
                               const float* __restrict__ bih1,
                               const float* __restrict__ Whh1,
                               const float* __restrict__ bhh1,
                               const float* __restrict__ fcw,
                               const float* __restrict__ fcb,
                               float* __restrict__ out)
{
    __shared__ __align__(16) float h0s[HID];
    __shared__ __align__(16) float h1s[HID];
    __shared__ __align__(16) float hp0s[G3];
    __shared__ __align__(16) float xt1s[G3];
    __shared__ __align__(16) float hp1s[G3];

    const int tid = threadIdx.x;
    const int b   = blockIdx.x;

    // ---- weight preload into registers ----
    float wA[64];          // thr<192: W_hh0 row g ; thr>=192: W_ih1 row g
    float wB[64];          // thr>=192: W_hh1 row g
    float biasA = 0.f, biasB = 0.f;
    if (tid < 192) {
#pragma unroll
        for (int j4 = 0; j4 < 16; ++j4) {
            float4 v = *(const float4*)&Whh0[tid * HID + j4 * 4];
            wA[4 * j4 + 0] = v.x; wA[4 * j4 + 1] = v.y;
            wA[4 * j4 + 2] = v.z; wA[4 * j4 + 3] = v.w;
        }
#pragma unroll
        for (int j = 0; j < 64; ++j) wB[j] = 0.f;
        biasA = bhh0[tid];
    } else {
        int g = tid - 192;
#pragma unroll
        for (int j4 = 0; j4 < 16; ++j4) {
            float4 v = *(const float4*)&Wih1[g * HID + j4 * 4];
            wA[4 * j4 + 0] = v.x; wA[4 * j4 + 1] = v.y;
            wA[4 * j4 + 2] = v.z; wA[4 * j4 + 3] = v.w;
            float4 u = *(const float4*)&Whh1[g * HID + j4 * 4];
            wB[4 * j4 + 0] = u.x; wB[4 * j4 + 1] = u.y;
            wB[4 * j4 + 2] = u.z; wB[4 * j4 + 3] = u.w;
        }
        biasA = bih1[g];
        biasB = bhh1[g];
    }

    float fw = 0.f;
    if (tid < 64) fw = fcw[tid];

    if (tid < 64) { h0s[tid] = 0.f; h1s[tid] = 0.f; }

    // xi prefetch, distance 2
    float x0r = 0.f, x0z = 0.f, x0n = 0.f, x1r = 0.f, x1z = 0.f, x1n = 0.f;
    if (tid < 64) {
        const float* p0 = &xi0[(size_t)(0 * BATCH + b) * G3];
        x0r = p0[tid]; x0z = p0[64 + tid]; x0n = p0[128 + tid];
        const float* p1 = &xi0[(size_t)(1 * BATCH + b) * G3];
        x1r = p1[tid]; x1z = p1[64 + tid]; x1n = p1[128 + tid];
    }
    __syncthreads();

    for (int t = 0; t < T_STEPS; ++t) {
        // issue prefetch for t+2 early (hides L2/L3 latency under 2 steps)
        float x2r = 0.f, x2z = 0.f, x2n = 0.f;
        if (tid < 64) {
            int tt = (t + 2 < T_STEPS) ? t + 2 : T_STEPS - 1;
            const float* p = &xi0[(size_t)(tt * BATCH + b) * G3];
            x2r = p[tid]; x2z = p[64 + tid]; x2n = p[128 + tid];
        }

        // ---- phase A: GEMVs ----
        if (tid < 192) {
            float a0 = 0.f, a1 = 0.f, a2 = 0.f, a3 = 0.f;
#pragma unroll
            for (int j4 = 0; j4 < 16; ++j4) {
                float4 h = *(const float4*)&h0s[4 * j4];
                a0 += wA[4 * j4 + 0] * h.x; a1 += wA[4 * j4 + 1] * h.y;
                a2 += wA[4 * j4 + 2] * h.z; a3 += wA[4 * j4 + 3] * h.w;
            }
            hp0s[tid] = biasA + ((a0 + a1) + (a2 + a3));
        } else if (t > 0) {
            int g = tid - 192;
            float a0 = 0.f, a1 = 0.f, a2 = 0.f, a3 = 0.f;
            float c0 = 0.f, c1 = 0.f, c2 = 0.f, c3 = 0.f;
#pragma unroll
            for (int j4 = 0; j4 < 16; ++j4) {
                float4 h0v = *(const float4*)&h0s[4 * j4];
                float4 h1v = *(const float4*)&h1s[4 * j4];
                a0 += wA[4 * j4 + 0] * h0v.x; a1 += wA[4 * j4 + 1] * h0v.y;
                a2 += wA[4 * j4 + 2] * h0v.z; a3 += wA[4 * j4 + 3] * h0v.w;
                c0 += wB[4 * j4 + 0] * h1v.x; c1 += wB[4 * j4 + 1] * h1v.y;
                c2 += wB[4 * j4 + 2] * h1v.z; c3 += wB[4 * j4 + 3] * h1v.w;
            }
            xt1s[g] = biasA + ((a0 + a1) + (a2 + a3));
            hp1s[g] = biasB + ((c0 + c1) + (c2 + c3));
        }
        __syncthreads();

        // ---- phase B: elementwise gate math ----
        if (tid < 64) {
            float r = sigf(x0r + hp0s[tid]);
            float z = sigf(x0z + hp0s[64 + tid]);
            float n = tanhf_(x0n + r * hp0s[128 + tid]);
            h0s[tid] = (1.f - z) * n + z * h0s[tid];
        } else if (tid < 128 && t > 0) {
            int j = tid - 64;
            float r = sigf(xt1s[j] + hp1s[j]);
            float z = sigf(xt1s[64 + j] + hp1s[64 + j]);
            float n = tanhf_(xt1s[128 + j] + r * hp1s[128 + j]);
            h1s[j] = (1.f - z) * n + z * h1s[j];
        }
        if (tid < 64) {
            x0r = x1r; x0z = x1z; x0n = x1n;
            x1r = x2r; x1z = x2z; x1n = x2n;
        }
        __syncthreads();
    }

    // ---- drain: layer-1 update for t = 511 ----
    if (tid >= 192) {
        int g = tid - 192;
        float a0 = 0.f, a1 = 0.f, a2 = 0.f, a3 = 0.f;
        float c0 = 0.f, c1 = 0.f, c2 = 0.f, c3 = 0.f;
#pragma unroll
        for (int j4 = 0; j4 < 16; ++j4) {
            float4 h0v = *(const float4*)&h0s[4 * j4];
            float4 h1v = *(const float4*)&h1s[4 * j4];
            a0 += wA[4 * j4 + 0] * h0v.x; a1 += wA[4 * j4 + 1] * h0v.y;
            a2 += wA[4 * j4 + 2] * h0v.z; a3 += wA[4 * j4 + 3] * h0v.w;
            c0 += wB[4 * j4 + 0] * h1v.x; c1 += wB[4 * j4 + 1] * h1v.y;
            c2 += wB[4 * j4 + 2] * h1v.z; c3 += wB[4 * j4 + 3] * h1v.w;
        }
        xt1s[g] = biasA + ((a0 + a1) + (a2 + a3));
        hp1s[g] = biasB + ((c0 + c1) + (c2 + c3));
    }
    __syncthreads();
    if (tid >= 64 && tid < 128) {
        int j = tid - 64;
        float r = sigf(xt1s[j] + hp1s[j]);
        float z = sigf(xt1s[64 + j] + hp1s[64 + j]);
        float n = tanhf_(xt1s[128 + j] + r * hp1s[128 + j]);
        h1s[j] = (1.f - z) * n + z * h1s[j];
    }
    __syncthreads();

    // ---- FC: out[b] = h1 . fc_w + fc_b ----
    if (tid < 64) {
        float p = h1s[tid] * fw;
#pragma unroll
        for (int off = 32; off >= 1; off >>= 1)
            p += __shfl_down(p, off);
        if (tid == 0) out[b] = p + fcb[0];
    }
}

extern "C" void kernel_launch(void* const* d_in, const int* in_sizes, int n_in,
                              void* d_out, int out_size, void* d_ws, size_t ws_size,
                              hipStream_t stream)
{
    const float* x    = (const float*)d_in[0];
    const float* Wih0 = (const float*)d_in[1];
    const float* Whh0 = (const float*)d_in[2];
    const float* bih0 = (const float*)d_in[3];
    const float* bhh0 = (const float*)d_in[4];
    const float* Wih1 = (const float*)d_in[5];
    const float* Whh1 = (const float*)d_in[6];
    const float* bih1 = (const float*)d_in[7];
    const float* bhh1 = (const float*)d_in[8];
    const float* fcw  = (const float*)d_in[9];
    const float* fcb  = (const float*)d_in[10];
    float* out = (float*)d_out;
    float* xi0 = (float*)d_ws;   // 512*64*192 fp32 = 25.2 MB

    hipLaunchKernelGGL(proj0_kernel, dim3(32768 / BM), dim3(512), 0, stream,
                       x, Wih0, bih0, xi0);
    hipLaunchKernelGGL(gru_seq_kernel, dim3(BATCH), dim3(384), 0, stream,
                       xi0, Whh0, bhh0, Wih1, bih1, Whh1, bhh1, fcw, fcb, out);
}

// Round 2
// 830.477 us; speedup vs baseline: 1.2495x; 1.2495x over previous
//
#include <hip/hip_runtime.h>

#define T_STEPS 512
#define BATCH   64
#define HID     64
#define G3      192      // 3*HID
#define DIN     2048

typedef float  f32x4  __attribute__((ext_vector_type(4)));
typedef short  short8 __attribute__((ext_vector_type(8)));

__device__ __forceinline__ unsigned short f2bf(float f) {
    unsigned int u = __builtin_bit_cast(unsigned int, f);
    unsigned int r = u + 0x7fffu + ((u >> 16) & 1u);   // RNE
    return (unsigned short)(r >> 16);
}

__device__ __forceinline__ float sigf(float x) {
    x = fminf(fmaxf(x, -30.f), 30.f);
    return 1.f / (1.f + __expf(-x));
}
__device__ __forceinline__ float tanhf_(float x) {
    float xc = fminf(fmaxf(x, -15.f), 15.f);
    float e = __expf(-2.f * xc);
    return (1.f - e) / (1.f + e);
}

// ---------------- Kernel 1: xi0 = x @ W_ih0^T + b_ih0  (bf16 MFMA) ----------
// M = B*T = 32768 (m = b*512 + t), N = 192, K = 2048.
// Output layout: xi0[m*192 + g] = xi0[b][t][g]  (chunk-load friendly).
#define BM  128
#define BK  64
#define LDA 72   // ushorts per row: 64 + 8 pad (breaks bank conflicts)
#define LDB 72

__launch_bounds__(512, 1)
__global__ void proj0_kernel(const float* __restrict__ x,
                             const float* __restrict__ Wih0,
                             const float* __restrict__ bih0,
                             float* __restrict__ xi0)
{
    __shared__ unsigned short Asm[BM * LDA];   // 18432 B
    __shared__ unsigned short Bsm[G3 * LDB];   // 27648 B

    const int tid  = threadIdx.x;
    const int wave = tid >> 6;
    const int lane = tid & 63;
    const int wm   = wave >> 2;      // 0..1  (M half)
    const int wn   = wave & 3;       // 0..3  (N quarter: 48 cols)
    const int m0   = blockIdx.x * BM;
    const int l16  = lane & 15;
    const int lk   = lane >> 4;      // 0..3

    f32x4 acc[4][3];
#pragma unroll
    for (int mi = 0; mi < 4; ++mi)
#pragma unroll
        for (int ni = 0; ni < 3; ++ni)
            acc[mi][ni] = (f32x4){0.f, 0.f, 0.f, 0.f};

    for (int kk = 0; kk < DIN; kk += BK) {
        // stage A tile: x[m0+r][kk+c], 128x64 fp32 -> bf16
#pragma unroll
        for (int it = 0; it < 4; ++it) {
            int fid = tid + it * 512;          // 0..2047 float4 slots
            int r   = fid >> 4;
            int c4  = fid & 15;
            float4 v = *(const float4*)&x[(size_t)(m0 + r) * DIN + kk + c4 * 4];
            uint2 pk;
            pk.x = (unsigned int)f2bf(v.x) | ((unsigned int)f2bf(v.y) << 16);
            pk.y = (unsigned int)f2bf(v.z) | ((unsigned int)f2bf(v.w) << 16);
            *(uint2*)&Asm[r * LDA + c4 * 4] = pk;
        }
        // stage B tile: Wih0[g][kk+c], 192x64 fp32 -> bf16
#pragma unroll
        for (int it = 0; it < 6; ++it) {
            int fid = tid + it * 512;          // 0..3071
            int r   = fid >> 4;
            int c4  = fid & 15;
            float4 v = *(const float4*)&Wih0[(size_t)r * DIN + kk + c4 * 4];
            uint2 pk;
            pk.x = (unsigned int)f2bf(v.x) | ((unsigned int)f2bf(v.y) << 16);
            pk.y = (unsigned int)f2bf(v.z) | ((unsigned int)f2bf(v.w) << 16);
            *(uint2*)&Bsm[r * LDB + c4 * 4] = pk;
        }
        __syncthreads();

#pragma unroll
        for (int ks = 0; ks < 2; ++ks) {
            const int kb = ks * 32 + lk * 8;   // same k-slot map for A and B
            short8 a[4], bfr[3];
#pragma unroll
            for (int mi = 0; mi < 4; ++mi)
                a[mi] = *(const short8*)&Asm[(wm * 64 + mi * 16 + l16) * LDA + kb];
#pragma unroll
            for (int ni = 0; ni < 3; ++ni)
                bfr[ni] = *(const short8*)&Bsm[(wn * 48 + ni * 16 + l16) * LDB + kb];
#pragma unroll
            for (int mi = 0; mi < 4; ++mi)
#pragma unroll
                for (int ni = 0; ni < 3; ++ni)
                    acc[mi][ni] = __builtin_amdgcn_mfma_f32_16x16x32_bf16(
                        a[mi], bfr[ni], acc[mi][ni], 0, 0, 0);
        }
        __syncthreads();
    }

    // epilogue: D layout col=lane&15, row=(lane>>4)*4+reg  [verified m89/m91]
#pragma unroll
    for (int ni = 0; ni < 3; ++ni) {
        int g = wn * 48 + ni * 16 + l16;
        float bias = bih0[g];
#pragma unroll
        for (int mi = 0; mi < 4; ++mi) {
#pragma unroll
            for (int r = 0; r < 4; ++r) {
                int m = m0 + wm * 64 + mi * 16 + lk * 4 + r;
                xi0[(size_t)m * G3 + g] = acc[mi][ni][r] + bias;
            }
        }
    }
}

// ---------------- Kernel 2: fused 2-layer GRU recurrence + FC ---------------
// One block per batch element, 192 threads = 3 waves, ONE barrier per step.
// Software pipeline (all cross-wave deps are produce@t -> consume@t+1):
//   wave0 @ step t: h0(t)     = gates(xi(t),  W_hh0 @ h0(t-1))
//   wave1 @ step t: xt1(t-1)  = W_ih1 @ h0(t-1) + b_ih1
//   wave2 @ step t: h1(t-2)   = gates(xt1(t-2), W_hh1 @ h1(t-3))
// Each thread holds its 3 gate rows (192 floats) in registers; gate merge is
// fully in-register. xi staged in 8-step LDS chunks (double-buffered).
__launch_bounds__(192, 1)
__global__ void gru_seq_kernel(const float* __restrict__ xi0,
                               const float* __restrict__ Whh0,
                               const float* __restrict__ bhh0,
                               const float* __restrict__ Wih1,
                               const float* __restrict__ bih1,
                               const float* __restrict__ Whh1,
                               const float* __restrict__ bhh1,
                               const float* __restrict__ fcw,
                               const float* __restrict__ fcb,
                               float* __restrict__ out)
{
    __shared__ __align__(16) float h0d[2][HID];      // double-buffered h0
    __shared__ __align__(16) float h1s[HID];         // wave2-private
    __shared__ __align__(16) float xt1d[2][G3];      // double-buffered xt1
    __shared__ __align__(16) float ring[2][8 * G3];  // xi chunks (2 x 6 KB)

    const int tid = threadIdx.x;
    const int w   = tid >> 6;       // wave id 0..2
    const int j   = tid & 63;       // lane
    const int b   = blockIdx.x;

    // ---- per-wave weight rows {j, 64+j, 128+j} into ONE shared reg array ----
    const float* Wb = (w == 0) ? Whh0 : (w == 1) ? Wih1 : Whh1;
    const float* Bb = (w == 0) ? bhh0 : (w == 1) ? bih1 : bhh1;
    float wreg[G3];
#pragma unroll
    for (int g = 0; g < 3; ++g) {
#pragma unroll
        for (int k4 = 0; k4 < 16; ++k4) {
            float4 v = *(const float4*)&Wb[(size_t)(g * 64 + j) * HID + k4 * 4];
            wreg[g * 64 + k4 * 4 + 0] = v.x;
            wreg[g * 64 + k4 * 4 + 1] = v.y;
            wreg[g * 64 + k4 * 4 + 2] = v.z;
            wreg[g * 64 + k4 * 4 + 3] = v.w;
        }
    }
    const float bR = Bb[j], bZ = Bb[64 + j], bN = Bb[128 + j];
    const float fw = (w == 2) ? fcw[j] : 0.f;

    float hreg = 0.f;                       // wave0: h0[j]; wave2: h1[j]
    if (tid < 64) { h0d[0][tid] = 0.f; h0d[1][tid] = 0.f; h1s[tid] = 0.f; }

    // ---- preload xi chunk 0 (steps 0..7): 1536 floats, 8 per thread ----
    {
        const float* src = &xi0[((size_t)b * T_STEPS) * G3];
        float4 a0 = *(const float4*)&src[tid * 8];
        float4 a1 = *(const float4*)&src[tid * 8 + 4];
        *(float4*)&ring[0][tid * 8]     = a0;
        *(float4*)&ring[0][tid * 8 + 4] = a1;
    }
    __syncthreads();

    float4 pf0, pf1;                        // chunk prefetch staging regs

    for (int t = 0; t < T_STEPS + 2; ++t) {
        // ---- xi chunk pipeline: issue at t%8==0, LDS-write at t%8==1 ----
        if ((t & 7) == 0 && t + 8 < T_STEPS) {
            const float* src = &xi0[((size_t)b * T_STEPS + t + 8) * G3];
            pf0 = *(const float4*)&src[tid * 8];
            pf1 = *(const float4*)&src[tid * 8 + 4];
        }
        if ((t & 7) == 1 && t + 7 < T_STEPS) {
            int buf = ((t + 7) >> 3) & 1;
            *(float4*)&ring[buf][tid * 8]     = pf0;
            *(float4*)&ring[buf][tid * 8 + 4] = pf1;
        }

        // ---- per-wave stage ----
        if (w == 0) {
            if (t < T_STEPS) {
                const float* hs = h0d[(t + 1) & 1];
                float aR = 0.f, aZ = 0.f, aN = 0.f;
                float cR = 0.f, cZ = 0.f, cN = 0.f;
#pragma unroll
                for (int k = 0; k < 64; k += 8) {
                    float4 ha = *(const float4*)&hs[k];
                    float4 hb = *(const float4*)&hs[k + 4];
                    aR += wreg[k+0]*ha.x; aR += wreg[k+1]*ha.y; aR += wreg[k+2]*ha.z; aR += wreg[k+3]*ha.w;
                    cR += wreg[k+4]*hb.x; cR += wreg[k+5]*hb.y; cR += wreg[k+6]*hb.z; cR += wreg[k+7]*hb.w;
                    aZ += wreg[64+k+0]*ha.x; aZ += wreg[64+k+1]*ha.y; aZ += wreg[64+k+2]*ha.z; aZ += wreg[64+k+3]*ha.w;
                    cZ += wreg[64+k+4]*hb.x; cZ += wreg[64+k+5]*hb.y; cZ += wreg[64+k+6]*hb.z; cZ += wreg[64+k+7]*hb.w;
                    aN += wreg[128+k+0]*ha.x; aN += wreg[128+k+1]*ha.y; aN += wreg[128+k+2]*ha.z; aN += wreg[128+k+3]*ha.w;
                    cN += wreg[128+k+4]*hb.x; cN += wreg[128+k+5]*hb.y; cN += wreg[128+k+6]*hb.z; cN += wreg[128+k+7]*hb.w;
                }
                const float* xs = &ring[(t >> 3) & 1][(t & 7) * G3];
                float r = sigf(xs[j]       + bR + aR + cR);
                float z = sigf(xs[64 + j]  + bZ + aZ + cZ);
                float n = tanhf_(xs[128 + j] + bN + (r * (bN * 0.f + aN + cN)));
                // note: n-gate form is tanh(xi_n + r*(W_hh0@h + b_hh0)) -> bias inside r*
                n = tanhf_(xs[128 + j] + r * (bN + aN + cN));
                hreg = (1.f - z) * n + z * hreg;
                h0d[t & 1][j] = hreg;
            }
        } else if (w == 1) {
            if (t >= 1 && t <= T_STEPS) {
                const float* hs = h0d[(t + 1) & 1];   // h0(t-1)
                float aR = 0.f, aZ = 0.f, aN = 0.f;
                float cR = 0.f, cZ = 0.f, cN = 0.f;
#pragma unroll
                for (int k = 0; k < 64; k += 8) {
                    float4 ha = *(const float4*)&hs[k];
                    float4 hb = *(const float4*)&hs[k + 4];
                    aR += wreg[k+0]*ha.x; aR += wreg[k+1]*ha.y; aR += wreg[k+2]*ha.z; aR += wreg[k+3]*ha.w;
                    cR += wreg[k+4]*hb.x; cR += wreg[k+5]*hb.y; cR += wreg[k+6]*hb.z; cR += wreg[k+7]*hb.w;
                    aZ += wreg[64+k+0]*ha.x; aZ += wreg[64+k+1]*ha.y; aZ += wreg[64+k+2]*ha.z; aZ += wreg[64+k+3]*ha.w;
                    cZ += wreg[64+k+4]*hb.x; cZ += wreg[64+k+5]*hb.y; cZ += wreg[64+k+6]*hb.z; cZ += wreg[64+k+7]*hb.w;
                    aN += wreg[128+k+0]*ha.x; aN += wreg[128+k+1]*ha.y; aN += wreg[128+k+2]*ha.z; aN += wreg[128+k+3]*ha.w;
                    cN += wreg[128+k+4]*hb.x; cN += wreg[128+k+5]*hb.y; cN += wreg[128+k+6]*hb.z; cN += wreg[128+k+7]*hb.w;
                }
                float* xt = xt1d[t & 1];
                xt[j]        = bR + aR + cR;
                xt[64 + j]   = bZ + aZ + cZ;
                xt[128 + j]  = bN + aN + cN;
            }
        } else {
            if (t >= 2) {
                const float* hs = h1s;                 // h1(t-3)
                float aR = 0.f, aZ = 0.f, aN = 0.f;
                float cR = 0.f, cZ = 0.f, cN = 0.f;
#pragma unroll
                for (int k = 0; k < 64; k += 8) {
                    float4 ha = *(const float4*)&hs[k];
                    float4 hb = *(const float4*)&hs[k + 4];
                    aR += wreg[k+0]*ha.x; aR += wreg[k+1]*ha.y; aR += wreg[k+2]*ha.z; aR += wreg[k+3]*ha.w;
                    cR += wreg[k+4]*hb.x; cR += wreg[k+5]*hb.y; cR += wreg[k+6]*hb.z; cR += wreg[k+7]*hb.w;
                    aZ += wreg[64+k+0]*ha.x; aZ += wreg[64+k+1]*ha.y; aZ += wreg[64+k+2]*ha.z; aZ += wreg[64+k+3]*ha.w;
                    cZ += wreg[64+k+4]*hb.x; cZ += wreg[64+k+5]*hb.y; cZ += wreg[64+k+6]*hb.z; cZ += wreg[64+k+7]*hb.w;
                    aN += wreg[128+k+0]*ha.x; aN += wreg[128+k+1]*ha.y; aN += wreg[128+k+2]*ha.z; aN += wreg[128+k+3]*ha.w;
                    cN += wreg[128+k+4]*hb.x; cN += wreg[128+k+5]*hb.y; cN += wreg[128+k+6]*hb.z; cN += wreg[128+k+7]*hb.w;
                }
                const float* xt = xt1d[(t + 1) & 1];   // xt1(t-2)
                float r = sigf(xt[j]       + bR + aR + cR);
                float z = sigf(xt[64 + j]  + bZ + aZ + cZ);
                float n = tanhf_(xt[128 + j] + r * (bN + aN + cN));
                hreg = (1.f - z) * n + z * hreg;
                h1s[j] = hreg;                         // becomes h1(t-2)
            }
        }
        __syncthreads();
    }

    // ---- FC: out[b] = h1(511) . fc_w + fc_b  (wave2 holds h1 in regs) ----
    if (w == 2) {
        float p = hreg * fw;
#pragma unroll
        for (int off = 32; off >= 1; off >>= 1)
            p += __shfl_down(p, off);
        if (j == 0) out[b] = p + fcb[0];
    }
}

extern "C" void kernel_launch(void* const* d_in, const int* in_sizes, int n_in,
                              void* d_out, int out_size, void* d_ws, size_t ws_size,
                              hipStream_t stream)
{
    const float* x    = (const float*)d_in[0];
    const float* Wih0 = (const float*)d_in[1];
    const float* Whh0 = (const float*)d_in[2];
    const float* bih0 = (const float*)d_in[3];
    const float* bhh0 = (const float*)d_in[4];
    const float* Wih1 = (const float*)d_in[5];
    const float* Whh1 = (const float*)d_in[6];
    const float* bih1 = (const float*)d_in[7];
    const float* bhh1 = (const float*)d_in[8];
    const float* fcw  = (const float*)d_in[9];
    const float* fcb  = (const float*)d_in[10];
    float* out = (float*)d_out;
    float* xi0 = (float*)d_ws;   // 64*512*192 fp32 = 25.2 MB

    hipLaunchKernelGGL(proj0_kernel, dim3(32768 / BM), dim3(512), 0, stream,
                       x, Wih0, bih0, xi0);
    hipLaunchKernelGGL(gru_seq_kernel, dim3(BATCH), dim3(192), 0, stream,
                       xi0, Whh0, bhh0, Wih1, bih1, Whh1, bhh1, fcw, fcb, out);
}

// Round 3
// 637.280 us; speedup vs baseline: 1.6283x; 1.3032x over previous
//
#include <hip/hip_runtime.h>

#define T_STEPS 512
#define BATCH   64
#define HID     64
#define G3      192      // 3*HID
#define DIN     2048
#define B_BLK   16
#define NBLK    4        // BATCH / B_BLK

typedef float  f32x4  __attribute__((ext_vector_type(4)));
typedef short  short8 __attribute__((ext_vector_type(8)));

__device__ __forceinline__ unsigned short f2bf(float f) {
    unsigned int u = __builtin_bit_cast(unsigned int, f);
    unsigned int r = u + 0x7fffu + ((u >> 16) & 1u);   // RNE
    return (unsigned short)(r >> 16);
}
__device__ __forceinline__ unsigned int pk2(float a, float b) {
    return (unsigned int)f2bf(a) | ((unsigned int)f2bf(b) << 16);
}
__device__ __forceinline__ float bflo(unsigned int u) {   // low bf16 -> f32
    return __builtin_bit_cast(float, u << 16);
}
__device__ __forceinline__ float bfhi(unsigned int u) {   // high bf16 -> f32
    return __builtin_bit_cast(float, u & 0xffff0000u);
}
// inf-graceful fast gates (no clamps needed): rcp(inf)=0, exp(-inf)=0
__device__ __forceinline__ float sigx(float x) {
    return __builtin_amdgcn_rcpf(1.f + __expf(-x));
}
__device__ __forceinline__ float tanhx(float s) {
    return 1.f - 2.f * __builtin_amdgcn_rcpf(1.f + __expf(2.f * s));
}

// ---------------- Kernel 1: xi = x @ W_ih0^T + b_ih0  (bf16 MFMA) ----------
// Output: bf16, layout xi[t][b][g] with g = gate*64 + row  (ring-friendly).
#define BM  128
#define BK  64
#define LDA 72
#define LDB 72

__launch_bounds__(512, 1)
__global__ void proj0_kernel(const float* __restrict__ x,
                             const float* __restrict__ Wih0,
                             const float* __restrict__ bih0,
                             unsigned short* __restrict__ xi)
{
    __shared__ unsigned short Asm[BM * LDA];
    __shared__ unsigned short Bsm[G3 * LDB];

    const int tid  = threadIdx.x;
    const int wave = tid >> 6;
    const int lane = tid & 63;
    const int wm   = wave >> 2;
    const int wn   = wave & 3;
    const int m0   = blockIdx.x * BM;
    const int l16  = lane & 15;
    const int lk   = lane >> 4;

    f32x4 acc[4][3];
#pragma unroll
    for (int mi = 0; mi < 4; ++mi)
#pragma unroll
        for (int ni = 0; ni < 3; ++ni)
            acc[mi][ni] = (f32x4){0.f, 0.f, 0.f, 0.f};

    for (int kk = 0; kk < DIN; kk += BK) {
#pragma unroll
        for (int it = 0; it < 4; ++it) {
            int fid = tid + it * 512;
            int r   = fid >> 4;
            int c4  = fid & 15;
            float4 v = *(const float4*)&x[(size_t)(m0 + r) * DIN + kk + c4 * 4];
            uint2 pk;
            pk.x = pk2(v.x, v.y);
            pk.y = pk2(v.z, v.w);
            *(uint2*)&Asm[r * LDA + c4 * 4] = pk;
        }
#pragma unroll
        for (int it = 0; it < 6; ++it) {
            int fid = tid + it * 512;
            int r   = fid >> 4;
            int c4  = fid & 15;
            float4 v = *(const float4*)&Wih0[(size_t)r * DIN + kk + c4 * 4];
            uint2 pk;
            pk.x = pk2(v.x, v.y);
            pk.y = pk2(v.z, v.w);
            *(uint2*)&Bsm[r * LDB + c4 * 4] = pk;
        }
        __syncthreads();

#pragma unroll
        for (int ks = 0; ks < 2; ++ks) {
            const int kb = ks * 32 + lk * 8;
            short8 a[4], bfr[3];
#pragma unroll
            for (int mi = 0; mi < 4; ++mi)
                a[mi] = *(const short8*)&Asm[(wm * 64 + mi * 16 + l16) * LDA + kb];
#pragma unroll
            for (int ni = 0; ni < 3; ++ni)
                bfr[ni] = *(const short8*)&Bsm[(wn * 48 + ni * 16 + l16) * LDB + kb];
#pragma unroll
            for (int mi = 0; mi < 4; ++mi)
#pragma unroll
                for (int ni = 0; ni < 3; ++ni)
                    acc[mi][ni] = __builtin_amdgcn_mfma_f32_16x16x32_bf16(
                        a[mi], bfr[ni], acc[mi][ni], 0, 0, 0);
        }
        __syncthreads();
    }

#pragma unroll
    for (int ni = 0; ni < 3; ++ni) {
        int g = wn * 48 + ni * 16 + l16;      // = gate*64 + row
        float bias = bih0[g];
#pragma unroll
        for (int mi = 0; mi < 4; ++mi) {
#pragma unroll
            for (int r = 0; r < 4; ++r) {
                int m  = m0 + wm * 64 + mi * 16 + lk * 4 + r;
                int t  = m & 511;
                int bb = m >> 9;
                xi[(size_t)(t * BATCH + bb) * G3 + g] = f2bf(acc[mi][ni][r] + bias);
            }
        }
    }
}

// ---------------- Kernel 2: MFMA-batched fused 2-layer GRU + FC ------------
// 4 blocks x 16 batch x 8 waves, ONE barrier per step.
// Waves 0-3: layer 0, wave w owns hidden rows 16w..16w+15 (all 3 gates):
//   6 MFMA (W_hh0 stationary, bias as C-init) + 4 gate units/lane in-register.
// Waves 4-7: layer 1, one step behind: 12 MFMA (W_ih1 on h0(t-1), W_hh1 on
//   h1(t-2)) + gates. h states fp32 in regs; bf16 h crosses via LDS.
__launch_bounds__(512, 1)
__global__ void gru_fused_kernel(const unsigned short* __restrict__ xi,
                                 const float* __restrict__ Whh0,
                                 const float* __restrict__ bhh0,
                                 const float* __restrict__ Wih1,
                                 const float* __restrict__ bih1,
                                 const float* __restrict__ Whh1,
                                 const float* __restrict__ bhh1,
                                 const float* __restrict__ fcw,
                                 const float* __restrict__ fcb,
                                 float* __restrict__ out)
{
    __shared__ unsigned short ring[2][8][B_BLK][200];  // 102.4 KB xi ring
    __shared__ unsigned short h0d[2][8][B_BLK][8];     // h0 bf16, [k/8][c][8]
    __shared__ unsigned short h1d[2][8][B_BLK][8];
    __shared__ float fcbuf[B_BLK][68];

    const int tid = threadIdx.x;
    const int w   = tid >> 6;        // wave 0..7
    const int l   = tid & 63;
    const int c   = l & 15;          // batch-in-block / MFMA col / A-row
    const int kg  = l >> 4;          // 0..3
    const int blk = blockIdx.x;
    const int jw  = (w & 3) * 16;    // hidden-row base owned by this wave
    const bool L0 = (w < 4);

    // ---- stationary weight fragments (A-operand), bias regs ----
    short8 fragA[6], fragB[6];
    float4 bA[3], bB[3];
    {
        const float* WA = L0 ? Whh0 : Wih1;
        const float* WB = L0 ? Whh0 : Whh1;       // L0: fragB unused
        const float* cA = L0 ? bhh0 : bih1;
        const float* cB = L0 ? bhh0 : bhh1;
#pragma unroll
        for (int g = 0; g < 3; ++g) {
#pragma unroll
            for (int ks = 0; ks < 2; ++ks) {
                const float* pa = &WA[(size_t)(g * 64 + jw + c) * HID + ks * 32 + kg * 8];
                float4 v0 = *(const float4*)&pa[0];
                float4 v1 = *(const float4*)&pa[4];
                short8 s;
                s[0]=(short)f2bf(v0.x); s[1]=(short)f2bf(v0.y);
                s[2]=(short)f2bf(v0.z); s[3]=(short)f2bf(v0.w);
                s[4]=(short)f2bf(v1.x); s[5]=(short)f2bf(v1.y);
                s[6]=(short)f2bf(v1.z); s[7]=(short)f2bf(v1.w);
                fragA[g * 2 + ks] = s;
                const float* pb = &WB[(size_t)(g * 64 + jw + c) * HID + ks * 32 + kg * 8];
                float4 u0 = *(const float4*)&pb[0];
                float4 u1 = *(const float4*)&pb[4];
                short8 sb;
                sb[0]=(short)f2bf(u0.x); sb[1]=(short)f2bf(u0.y);
                sb[2]=(short)f2bf(u0.z); sb[3]=(short)f2bf(u0.w);
                sb[4]=(short)f2bf(u1.x); sb[5]=(short)f2bf(u1.y);
                sb[6]=(short)f2bf(u1.z); sb[7]=(short)f2bf(u1.w);
                fragB[g * 2 + ks] = sb;
            }
            bA[g] = *(const float4*)&cA[g * 64 + jw + kg * 4];
            bB[g] = *(const float4*)&cB[g * 64 + jw + kg * 4];
        }
    }

    float hst[4] = {0.f, 0.f, 0.f, 0.f};   // L0: h0[c][jw+4kg+q]; L1: h1[...]

    // ---- zero h buffers, preload xi chunk 0 ----
#pragma unroll
    for (int i = 0; i < 4; ++i) {
        int e = tid + i * 512;               // 2048 elements per array
        ((unsigned short*)h0d)[e] = 0;
        ((unsigned short*)h1d)[e] = 0;
    }
#pragma unroll
    for (int i = 0; i < 6; ++i) {
        int u = tid + i * 512;               // 3072 float4-units per chunk
        int t_off = u / 384, rem = u % 384;
        int cc = rem / 24, pos = rem % 24;
        float4 v = *(const float4*)&xi[((size_t)((t_off) * BATCH) + blk * B_BLK + cc) * G3 + pos * 8];
        *(float4*)&ring[0][t_off][cc][pos * 8] = v;
    }
    __syncthreads();

    float4 st[6];   // chunk staging regs

    for (int t = 0; t <= T_STEPS; ++t) {
        // ---- xi ring: issue at t%8==0, LDS-write at t%8==1 ----
        if ((t & 7) == 0 && t + 8 < T_STEPS) {
#pragma unroll
            for (int i = 0; i < 6; ++i) {
                int u = tid + i * 512;
                int t_off = u / 384, rem = u % 384;
                int cc = rem / 24, pos = rem % 24;
                st[i] = *(const float4*)&xi[((size_t)((t + 8 + t_off) * BATCH) + blk * B_BLK + cc) * G3 + pos * 8];
            }
        }
        if ((t & 7) == 1 && t + 7 < T_STEPS) {
            int buf = ((t + 7) >> 3) & 1;
#pragma unroll
            for (int i = 0; i < 6; ++i) {
                int u = tid + i * 512;
                int t_off = u / 384, rem = u % 384;
                int cc = rem / 24, pos = rem % 24;
                *(float4*)&ring[buf][t_off][cc][pos * 8] = st[i];
            }
        }

        if (L0) {
            if (t < T_STEPS) {
                const int pb = (t + 1) & 1;                    // (t-1)&1
                short8 x0 = *(const short8*)&h0d[pb][kg][c][0];       // k 0..31
                short8 x1 = *(const short8*)&h0d[pb][4 + kg][c][0];   // k 32..63
                f32x4 a0 = (f32x4){bA[0].x, bA[0].y, bA[0].z, bA[0].w};
                f32x4 a1 = (f32x4){bA[1].x, bA[1].y, bA[1].z, bA[1].w};
                f32x4 a2 = (f32x4){bA[2].x, bA[2].y, bA[2].z, bA[2].w};
                a0 = __builtin_amdgcn_mfma_f32_16x16x32_bf16(fragA[0], x0, a0, 0, 0, 0);
                a0 = __builtin_amdgcn_mfma_f32_16x16x32_bf16(fragA[1], x1, a0, 0, 0, 0);
                a1 = __builtin_amdgcn_mfma_f32_16x16x32_bf16(fragA[2], x0, a1, 0, 0, 0);
                a1 = __builtin_amdgcn_mfma_f32_16x16x32_bf16(fragA[3], x1, a1, 0, 0, 0);
                a2 = __builtin_amdgcn_mfma_f32_16x16x32_bf16(fragA[4], x0, a2, 0, 0, 0);
                a2 = __builtin_amdgcn_mfma_f32_16x16x32_bf16(fragA[5], x1, a2, 0, 0, 0);

                const int rb = (t >> 3) & 1, t8 = t & 7;
                uint2 xr = *(const uint2*)&ring[rb][t8][c][jw + kg * 4];
                uint2 xz = *(const uint2*)&ring[rb][t8][c][64 + jw + kg * 4];
                uint2 xn = *(const uint2*)&ring[rb][t8][c][128 + jw + kg * 4];
                float xrf[4] = {bflo(xr.x), bfhi(xr.x), bflo(xr.y), bfhi(xr.y)};
                float xzf[4] = {bflo(xz.x), bfhi(xz.x), bflo(xz.y), bfhi(xz.y)};
                float xnf[4] = {bflo(xn.x), bfhi(xn.x), bflo(xn.y), bfhi(xn.y)};
#pragma unroll
                for (int q = 0; q < 4; ++q) {
                    float r = sigx(xrf[q] + a0[q]);
                    float z = sigx(xzf[q] + a1[q]);
                    float n = tanhx(fmaf(r, a2[q], xnf[q]));
                    hst[q] = n + z * (hst[q] - n);
                }
                const int chunk = 2 * (w & 3) + (kg >> 1);
                uint2 hw;
                hw.x = pk2(hst[0], hst[1]);
                hw.y = pk2(hst[2], hst[3]);
                *(uint2*)&h0d[t & 1][chunk][c][(kg & 1) * 4] = hw;
            }
        } else {
            if (t >= 1) {
                const int pb = (t + 1) & 1;    // h0d[(t-1)&1] = h0(t-1)
                const int p1 = t & 1;          // h1d[(t-2)&1] = h1(t-2)
                short8 x0 = *(const short8*)&h0d[pb][kg][c][0];
                short8 x1 = *(const short8*)&h0d[pb][4 + kg][c][0];
                short8 y0 = *(const short8*)&h1d[p1][kg][c][0];
                short8 y1 = *(const short8*)&h1d[p1][4 + kg][c][0];
                f32x4 i0 = (f32x4){bA[0].x, bA[0].y, bA[0].z, bA[0].w};
                f32x4 i1 = (f32x4){bA[1].x, bA[1].y, bA[1].z, bA[1].w};
                f32x4 i2 = (f32x4){bA[2].x, bA[2].y, bA[2].z, bA[2].w};
                f32x4 h0a = (f32x4){bB[0].x, bB[0].y, bB[0].z, bB[0].w};
                f32x4 h1a = (f32x4){bB[1].x, bB[1].y, bB[1].z, bB[1].w};
                f32x4 h2a = (f32x4){bB[2].x, bB[2].y, bB[2].z, bB[2].w};
                i0  = __builtin_amdgcn_mfma_f32_16x16x32_bf16(fragA[0], x0, i0, 0, 0, 0);
                i0  = __builtin_amdgcn_mfma_f32_16x16x32_bf16(fragA[1], x1, i0, 0, 0, 0);
                i1  = __builtin_amdgcn_mfma_f32_16x16x32_bf16(fragA[2], x0, i1, 0, 0, 0);
                i1  = __builtin_amdgcn_mfma_f32_16x16x32_bf16(fragA[3], x1, i1, 0, 0, 0);
                i2  = __builtin_amdgcn_mfma_f32_16x16x32_bf16(fragA[4], x0, i2, 0, 0, 0);
                i2  = __builtin_amdgcn_mfma_f32_16x16x32_bf16(fragA[5], x1, i2, 0, 0, 0);
                h0a = __builtin_amdgcn_mfma_f32_16x16x32_bf16(fragB[0], y0, h0a, 0, 0, 0);
                h0a = __builtin_amdgcn_mfma_f32_16x16x32_bf16(fragB[1], y1, h0a, 0, 0, 0);
                h1a = __builtin_amdgcn_mfma_f32_16x16x32_bf16(fragB[2], y0, h1a, 0, 0, 0);
                h1a = __builtin_amdgcn_mfma_f32_16x16x32_bf16(fragB[3], y1, h1a, 0, 0, 0);
                h2a = __builtin_amdgcn_mfma_f32_16x16x32_bf16(fragB[4], y0, h2a, 0, 0, 0);
                h2a = __builtin_amdgcn_mfma_f32_16x16x32_bf16(fragB[5], y1, h2a, 0, 0, 0);
#pragma unroll
                for (int q = 0; q < 4; ++q) {
                    float r = sigx(i0[q] + h0a[q]);
                    float z = sigx(i1[q] + h1a[q]);
                    float n = tanhx(fmaf(r, h2a[q], i2[q]));
                    hst[q] = n + z * (hst[q] - n);
                }
                const int chunk = 2 * (w & 3) + (kg >> 1);
                uint2 hw;
                hw.x = pk2(hst[0], hst[1]);
                hw.y = pk2(hst[2], hst[3]);
                *(uint2*)&h1d[(t + 1) & 1][chunk][c][(kg & 1) * 4] = hw;  // h1(t-1)
            }
        }
        __syncthreads();
    }

    // ---- FC: out[b] = h1(511) . fc_w + fc_b ----
    if (!L0) {
#pragma unroll
        for (int q = 0; q < 4; ++q)
            fcbuf[c][jw + kg * 4 + q] = hst[q];
    }
    __syncthreads();
    if (w == 0) {
        float p = 0.f;
#pragma unroll
        for (int jj = 0; jj < 16; ++jj)
            p += fcbuf[c][kg * 16 + jj] * fcw[kg * 16 + jj];
        p += __shfl_xor(p, 16);
        p += __shfl_xor(p, 32);
        if (kg == 0) out[blk * B_BLK + c] = p + fcb[0];
    }
}

extern "C" void kernel_launch(void* const* d_in, const int* in_sizes, int n_in,
                              void* d_out, int out_size, void* d_ws, size_t ws_size,
                              hipStream_t stream)
{
    const float* x    = (const float*)d_in[0];
    const float* Wih0 = (const float*)d_in[1];
    const float* Whh0 = (const float*)d_in[2];
    const float* bih0 = (const float*)d_in[3];
    const float* bhh0 = (const float*)d_in[4];
    const float* Wih1 = (const float*)d_in[5];
    const float* Whh1 = (const float*)d_in[6];
    const float* bih1 = (const float*)d_in[7];
    const float* bhh1 = (const float*)d_in[8];
    const float* fcw  = (const float*)d_in[9];
    const float* fcb  = (const float*)d_in[10];
    float* out = (float*)d_out;
    unsigned short* xi = (unsigned short*)d_ws;   // 512*64*192 bf16 = 12.6 MB

    hipLaunchKernelGGL(proj0_kernel, dim3(32768 / BM), dim3(512), 0, stream,
                       x, Wih0, bih0, xi);
    hipLaunchKernelGGL(gru_fused_kernel, dim3(NBLK), dim3(512), 0, stream,
                       xi, Whh0, bhh0, Wih1, bih1, Whh1, bhh1, fcw, fcb, out);
}

// Round 4
// 469.860 us; speedup vs baseline: 2.2085x; 1.3563x over previous
//
#include <hip/hip_runtime.h>

#define T_STEPS 512
#define BATCH   64
#define HID     64
#define G3      192      // 3*HID
#define DIN     2048
#define B_BLK   16
#define NBLK    4        // BATCH / B_BLK

typedef float  f32x4  __attribute__((ext_vector_type(4)));
typedef short  short8 __attribute__((ext_vector_type(8)));

__device__ __forceinline__ unsigned short f2bf(float f) {
    unsigned int u = __builtin_bit_cast(unsigned int, f);
    unsigned int r = u + 0x7fffu + ((u >> 16) & 1u);   // RNE
    return (unsigned short)(r >> 16);
}
// HW packed f32->bf16 (RNE), 1 instruction
__device__ __forceinline__ unsigned int cvtpk(float a, float b) {
    unsigned int r;
    asm("v_cvt_pk_bf16_f32 %0, %1, %2" : "=v"(r) : "v"(a), "v"(b));
    return r;
}
__device__ __forceinline__ float bflo(unsigned int u) {
    return __builtin_bit_cast(float, u << 16);
}
__device__ __forceinline__ float bfhi(unsigned int u) {
    return __builtin_bit_cast(float, u & 0xffff0000u);
}
// inf-graceful fast gates: rcp(inf)=0, exp(-inf)=0
__device__ __forceinline__ float sigx(float x) {
    return __builtin_amdgcn_rcpf(1.f + __expf(-x));
}
__device__ __forceinline__ float tanhx(float s) {
    return 1.f - 2.f * __builtin_amdgcn_rcpf(1.f + __expf(2.f * s));
}
// barrier WITHOUT vmcnt drain: orders LDS (lgkmcnt) only; "memory" clobbers
// fence compiler motion on both sides. Keeps global prefetch in flight.
__device__ __forceinline__ void wg_barrier() {
    asm volatile("s_waitcnt lgkmcnt(0)" ::: "memory");
    __builtin_amdgcn_s_barrier();
    asm volatile("" ::: "memory");
}

// ---------------- Kernel 1: xi = x @ W_ih0^T + b_ih0  (bf16 MFMA) ----------
// Output: bf16, layout xi[t][b][g], g = gate*64 + row.
// Software-pipelined staging: next tile's global loads ride through the MFMA
// phase (raw barriers, no vmcnt drain).
#define BM  128
#define BK  64
#define LDA 72
#define LDB 72

__launch_bounds__(512, 1)
__global__ void proj0_kernel(const float* __restrict__ x,
                             const float* __restrict__ Wih0,
                             const float* __restrict__ bih0,
                             unsigned short* __restrict__ xi)
{
    __shared__ unsigned short Asm[BM * LDA];
    __shared__ unsigned short Bsm[G3 * LDB];

    const int tid  = threadIdx.x;
    const int wave = tid >> 6;
    const int lane = tid & 63;
    const int wm   = wave >> 2;
    const int wn   = wave & 3;
    const int m0   = blockIdx.x * BM;
    const int l16  = lane & 15;
    const int lk   = lane >> 4;
    const int rA   = tid >> 4;       // 0..31
    const int c4   = tid & 15;

    const float* xb = x    + (size_t)(m0 + rA) * DIN + c4 * 4;
    const float* wb = Wih0 + (size_t)rA        * DIN + c4 * 4;
    unsigned short* ap = Asm + rA * LDA + c4 * 4;
    unsigned short* bp = Bsm + rA * LDB + c4 * 4;

    f32x4 acc[4][3];
#pragma unroll
    for (int mi = 0; mi < 4; ++mi)
#pragma unroll
        for (int ni = 0; ni < 3; ++ni)
            acc[mi][ni] = (f32x4){0.f, 0.f, 0.f, 0.f};

    float4 stA[4], stB[6];
    // prologue: issue loads for k-tile 0
#pragma unroll
    for (int it = 0; it < 4; ++it) stA[it] = *(const float4*)(xb + it * 32 * DIN);
#pragma unroll
    for (int it = 0; it < 6; ++it) stB[it] = *(const float4*)(wb + it * 32 * DIN);

    for (int kt = 0; kt < DIN / BK; ++kt) {
        // pack current regs -> LDS (vmcnt waits inserted here by compiler)
#pragma unroll
        for (int it = 0; it < 4; ++it) {
            uint2 pk;
            pk.x = cvtpk(stA[it].x, stA[it].y);
            pk.y = cvtpk(stA[it].z, stA[it].w);
            *(uint2*)(ap + it * 32 * LDA) = pk;
        }
#pragma unroll
        for (int it = 0; it < 6; ++it) {
            uint2 pk;
            pk.x = cvtpk(stB[it].x, stB[it].y);
            pk.y = cvtpk(stB[it].z, stB[it].w);
            *(uint2*)(bp + it * 32 * LDB) = pk;
        }
        // issue next tile's loads; they stay in flight through the MFMA phase
        if (kt + 1 < DIN / BK) {
            const int kk = (kt + 1) * BK;
#pragma unroll
            for (int it = 0; it < 4; ++it) stA[it] = *(const float4*)(xb + kk + it * 32 * DIN);
#pragma unroll
            for (int it = 0; it < 6; ++it) stB[it] = *(const float4*)(wb + kk + it * 32 * DIN);
        }
        wg_barrier();

#pragma unroll
        for (int ks = 0; ks < 2; ++ks) {
            const int kb = ks * 32 + lk * 8;
            short8 a[4], bfr[3];
#pragma unroll
            for (int mi = 0; mi < 4; ++mi)
                a[mi] = *(const short8*)&Asm[(wm * 64 + mi * 16 + l16) * LDA + kb];
#pragma unroll
            for (int ni = 0; ni < 3; ++ni)
                bfr[ni] = *(const short8*)&Bsm[(wn * 48 + ni * 16 + l16) * LDB + kb];
#pragma unroll
            for (int mi = 0; mi < 4; ++mi)
#pragma unroll
                for (int ni = 0; ni < 3; ++ni)
                    acc[mi][ni] = __builtin_amdgcn_mfma_f32_16x16x32_bf16(
                        a[mi], bfr[ni], acc[mi][ni], 0, 0, 0);
        }
        wg_barrier();
    }

#pragma unroll
    for (int ni = 0; ni < 3; ++ni) {
        int g = wn * 48 + ni * 16 + l16;      // = gate*64 + row
        float bias = bih0[g];
#pragma unroll
        for (int mi = 0; mi < 4; ++mi) {
#pragma unroll
            for (int r = 0; r < 4; ++r) {
                int m  = m0 + wm * 64 + mi * 16 + lk * 4 + r;
                int t  = m & 511;
                int bb = m >> 9;
                xi[(size_t)(t * BATCH + bb) * G3 + g] = f2bf(acc[mi][ni][r] + bias);
            }
        }
    }
}

// ---------------- Kernel 2: MFMA-batched fused 2-layer GRU + FC ------------
// 4 blocks x 16 batch x 8 waves, ONE raw barrier per step.
// Waves 0-3 (L0): h0(t) via 6 MFMA; xi comes global->reg, 2-step prefetch.
// Waves 4-7 (L1): one step behind, 12 MFMA on h0(t-1) and h1(t-2).
__launch_bounds__(512, 1)
__global__ void gru_fused_kernel(const unsigned short* __restrict__ xi,
                                 const float* __restrict__ Whh0,
                                 const float* __restrict__ bhh0,
                                 const float* __restrict__ Wih1,
                                 const float* __restrict__ bih1,
                                 const float* __restrict__ Whh1,
                                 const float* __restrict__ bhh1,
                                 const float* __restrict__ fcw,
                                 const float* __restrict__ fcb,
                                 float* __restrict__ out)
{
    __shared__ __align__(16) unsigned short h0d[2][8][B_BLK][8];
    __shared__ __align__(16) unsigned short h1d[2][8][B_BLK][8];
    __shared__ float fcbuf[B_BLK][68];

    const int tid = threadIdx.x;
    const int w   = tid >> 6;
    const int l   = tid & 63;
    const int c   = l & 15;
    const int kg  = l >> 4;
    const int blk = blockIdx.x;
    const int jw  = (w & 3) * 16;
    const bool L0 = (w < 4);

    // ---- stationary weight fragments + bias regs ----
    short8 fragA[6], fragB[6];
    f32x4 cA[3], cB[3];
    {
        const float* WA = L0 ? Whh0 : Wih1;
        const float* WB = L0 ? Whh0 : Whh1;
        const float* bA = L0 ? bhh0 : bih1;
        const float* bB = L0 ? bhh0 : bhh1;
#pragma unroll
        for (int g = 0; g < 3; ++g) {
#pragma unroll
            for (int ks = 0; ks < 2; ++ks) {
                const float* pa = &WA[(size_t)(g * 64 + jw + c) * HID + ks * 32 + kg * 8];
                float4 v0 = *(const float4*)&pa[0];
                float4 v1 = *(const float4*)&pa[4];
                short8 s;
                s[0]=(short)f2bf(v0.x); s[1]=(short)f2bf(v0.y);
                s[2]=(short)f2bf(v0.z); s[3]=(short)f2bf(v0.w);
                s[4]=(short)f2bf(v1.x); s[5]=(short)f2bf(v1.y);
                s[6]=(short)f2bf(v1.z); s[7]=(short)f2bf(v1.w);
                fragA[g * 2 + ks] = s;
                const float* pb = &WB[(size_t)(g * 64 + jw + c) * HID + ks * 32 + kg * 8];
                float4 u0 = *(const float4*)&pb[0];
                float4 u1 = *(const float4*)&pb[4];
                short8 sb;
                sb[0]=(short)f2bf(u0.x); sb[1]=(short)f2bf(u0.y);
                sb[2]=(short)f2bf(u0.z); sb[3]=(short)f2bf(u0.w);
                sb[4]=(short)f2bf(u1.x); sb[5]=(short)f2bf(u1.y);
                sb[6]=(short)f2bf(u1.z); sb[7]=(short)f2bf(u1.w);
                fragB[g * 2 + ks] = sb;
            }
            float4 va = *(const float4*)&bA[g * 64 + jw + kg * 4];
            float4 vb = *(const float4*)&bB[g * 64 + jw + kg * 4];
            cA[g] = (f32x4){va.x, va.y, va.z, va.w};
            cB[g] = (f32x4){vb.x, vb.y, vb.z, vb.w};
        }
    }

    float hst[4] = {0.f, 0.f, 0.f, 0.f};

    // zero h buffers
#pragma unroll
    for (int i = 0; i < 4; ++i) {
        int e = tid + i * 512;
        ((unsigned short*)h0d)[e] = 0;
        ((unsigned short*)h1d)[e] = 0;
    }

    // xi prefetch base + prologue loads (L0 lanes only), depth 2
    const unsigned short* xp =
        xi + (size_t)(blk * B_BLK + c) * G3 + jw + kg * 4;
    uint2 pA[3], pB[3];
    if (L0) {
        pA[0] = *(const uint2*)(xp);
        pA[1] = *(const uint2*)(xp + 64);
        pA[2] = *(const uint2*)(xp + 128);
        const unsigned short* p1 = xp + (size_t)BATCH * G3;
        pB[0] = *(const uint2*)(p1);
        pB[1] = *(const uint2*)(p1 + 64);
        pB[2] = *(const uint2*)(p1 + 128);
    }
    __syncthreads();

    auto gru_step = [&](int t, uint2 (&cur)[3]) {
        if (L0) {
            if (t < T_STEPS) {
                const int pb = (t + 1) & 1;                    // (t-1)&1
                short8 x0 = *(const short8*)&h0d[pb][kg][c][0];
                short8 x1 = *(const short8*)&h0d[pb][4 + kg][c][0];
                f32x4 a0 = cA[0], a1 = cA[1], a2 = cA[2];
                a0 = __builtin_amdgcn_mfma_f32_16x16x32_bf16(fragA[0], x0, a0, 0, 0, 0);
                a0 = __builtin_amdgcn_mfma_f32_16x16x32_bf16(fragA[1], x1, a0, 0, 0, 0);
                a1 = __builtin_amdgcn_mfma_f32_16x16x32_bf16(fragA[2], x0, a1, 0, 0, 0);
                a1 = __builtin_amdgcn_mfma_f32_16x16x32_bf16(fragA[3], x1, a1, 0, 0, 0);
                a2 = __builtin_amdgcn_mfma_f32_16x16x32_bf16(fragA[4], x0, a2, 0, 0, 0);
                a2 = __builtin_amdgcn_mfma_f32_16x16x32_bf16(fragA[5], x1, a2, 0, 0, 0);

                // consume xi(t) from regs
                float xrf[4] = {bflo(cur[0].x), bfhi(cur[0].x), bflo(cur[0].y), bfhi(cur[0].y)};
                float xzf[4] = {bflo(cur[1].x), bfhi(cur[1].x), bflo(cur[1].y), bfhi(cur[1].y)};
                float xnf[4] = {bflo(cur[2].x), bfhi(cur[2].x), bflo(cur[2].y), bfhi(cur[2].y)};
                // issue prefetch for t+2 (regs now dead); rides across barriers
                if (t + 2 < T_STEPS) {
                    const unsigned short* p = xp + (size_t)(t + 2) * (BATCH * G3);
                    cur[0] = *(const uint2*)(p);
                    cur[1] = *(const uint2*)(p + 64);
                    cur[2] = *(const uint2*)(p + 128);
                }
#pragma unroll
                for (int q = 0; q < 4; ++q) {
                    float r = sigx(xrf[q] + a0[q]);
                    float z = sigx(xzf[q] + a1[q]);
                    float n = tanhx(fmaf(r, a2[q], xnf[q]));
                    hst[q] = n + z * (hst[q] - n);
                }
                const int chunk = 2 * (w & 3) + (kg >> 1);
                uint2 hw;
                hw.x = cvtpk(hst[0], hst[1]);
                hw.y = cvtpk(hst[2], hst[3]);
                *(uint2*)&h0d[t & 1][chunk][c][(kg & 1) * 4] = hw;
            }
        } else {
            if (t >= 1 && t <= T_STEPS) {
                const int pb = (t + 1) & 1;    // h0(t-1)
                const int p1 = t & 1;          // h1(t-2)
                short8 x0 = *(const short8*)&h0d[pb][kg][c][0];
                short8 x1 = *(const short8*)&h0d[pb][4 + kg][c][0];
                short8 y0 = *(const short8*)&h1d[p1][kg][c][0];
                short8 y1 = *(const short8*)&h1d[p1][4 + kg][c][0];
                f32x4 i0 = cA[0], i1 = cA[1], i2 = cA[2];
                f32x4 h0a = cB[0], h1a = cB[1], h2a = cB[2];
                i0  = __builtin_amdgcn_mfma_f32_16x16x32_bf16(fragA[0], x0, i0, 0, 0, 0);
                i0  = __builtin_amdgcn_mfma_f32_16x16x32_bf16(fragA[1], x1, i0, 0, 0, 0);
                i1  = __builtin_amdgcn_mfma_f32_16x16x32_bf16(fragA[2], x0, i1, 0, 0, 0);
                i1  = __builtin_amdgcn_mfma_f32_16x16x32_bf16(fragA[3], x1, i1, 0, 0, 0);
                i2  = __builtin_amdgcn_mfma_f32_16x16x32_bf16(fragA[4], x0, i2, 0, 0, 0);
                i2  = __builtin_amdgcn_mfma_f32_16x16x32_bf16(fragA[5], x1, i2, 0, 0, 0);
                h0a = __builtin_amdgcn_mfma_f32_16x16x32_bf16(fragB[0], y0, h0a, 0, 0, 0);
                h0a = __builtin_amdgcn_mfma_f32_16x16x32_bf16(fragB[1], y1, h0a, 0, 0, 0);
                h1a = __builtin_amdgcn_mfma_f32_16x16x32_bf16(fragB[2], y0, h1a, 0, 0, 0);
                h1a = __builtin_amdgcn_mfma_f32_16x16x32_bf16(fragB[3], y1, h1a, 0, 0, 0);
                h2a = __builtin_amdgcn_mfma_f32_16x16x32_bf16(fragB[4], y0, h2a, 0, 0, 0);
                h2a = __builtin_amdgcn_mfma_f32_16x16x32_bf16(fragB[5], y1, h2a, 0, 0, 0);
#pragma unroll
                for (int q = 0; q < 4; ++q) {
                    float r = sigx(i0[q] + h0a[q]);
                    float z = sigx(i1[q] + h1a[q]);
                    float n = tanhx(fmaf(r, h2a[q], i2[q]));
                    hst[q] = n + z * (hst[q] - n);
                }
                const int chunk = 2 * (w & 3) + (kg >> 1);
                uint2 hw;
                hw.x = cvtpk(hst[0], hst[1]);
                hw.y = cvtpk(hst[2], hst[3]);
                *(uint2*)&h1d[(t + 1) & 1][chunk][c][(kg & 1) * 4] = hw;  // h1(t-1)
            }
        }
        wg_barrier();
    };

    for (int tt = 0; tt < T_STEPS + 2; tt += 2) {   // 514 steps, even count
        gru_step(tt, pA);
        gru_step(tt + 1, pB);
    }

    // ---- FC: out[b] = h1(511) . fc_w + fc_b ----
    if (!L0) {
#pragma unroll
        for (int q = 0; q < 4; ++q)
            fcbuf[c][jw + kg * 4 + q] = hst[q];
    }
    __syncthreads();
    if (w == 0) {
        float p = 0.f;
#pragma unroll
        for (int jj = 0; jj < 16; ++jj)
            p += fcbuf[c][kg * 16 + jj] * fcw[kg * 16 + jj];
        p += __shfl_xor(p, 16);
        p += __shfl_xor(p, 32);
        if (kg == 0) out[blk * B_BLK + c] = p + fcb[0];
    }
}

extern "C" void kernel_launch(void* const* d_in, const int* in_sizes, int n_in,
                              void* d_out, int out_size, void* d_ws, size_t ws_size,
                              hipStream_t stream)
{
    const float* x    = (const float*)d_in[0];
    const float* Wih0 = (const float*)d_in[1];
    const float* Whh0 = (const float*)d_in[2];
    const float* bih0 = (const float*)d_in[3];
    const float* bhh0 = (const float*)d_in[4];
    const float* Wih1 = (const float*)d_in[5];
    const float* Whh1 = (const float*)d_in[6];
    const float* bih1 = (const float*)d_in[7];
    const float* bhh1 = (const float*)d_in[8];
    const float* fcw  = (const float*)d_in[9];
    const float* fcb  = (const float*)d_in[10];
    float* out = (float*)d_out;
    unsigned short* xi = (unsigned short*)d_ws;   // 512*64*192 bf16 = 12.6 MB

    hipLaunchKernelGGL(proj0_kernel, dim3(32768 / BM), dim3(512), 0, stream,
                       x, Wih0, bih0, xi);
    hipLaunchKernelGGL(gru_fused_kernel, dim3(NBLK), dim3(512), 0, stream,
                       xi, Whh0, bhh0, Wih1, bih1, Whh1, bhh1, fcw, fcb, out);
}